// Round 14
// baseline (107.118 us; speedup 1.0000x reference)
//
#include <hip/hip_runtime.h>

#define NODES 50000
#define NEDGES 800000
#define NIN 512
#define NHID 64

#define NB 391        // coarse buckets: row >> 7, 128 rows each
#define BCAP 2560     // per-bucket edge capacity (mean 2046, +11 sigma)
#define EB 4096       // edges per binA block
#define NBA 196       // binA blocks: 196*4096 >= 800000

#define XSTR 268      // LDS row stride in u32: 256 data + 12 pad (16B-aligned rows)

typedef __attribute__((ext_vector_type(8))) short short8v;           // 8 bf16
typedef __attribute__((ext_vector_type(8))) unsigned short ushort8v; // 8 bf16
typedef __attribute__((ext_vector_type(4))) float f32x4;
typedef __attribute__((ext_vector_type(4))) unsigned int uint4v;

// ws layout in 4-byte words
#define H_OFF    0          // 1,600,000 words: h bf16 (3.2M elems)
#define WBF_OFF  1600000    // 16,384 words: W bf16
#define GCUR_OFF 1616384    // 512 words: bucket cursors
#define RMETA_OFF 1616896   // 100,000 words: int2 {start, deg} per row
#define ECV2_OFF 1716896    // 2,001,920 words: NB x BCAP x int2
// end = 3,718,816 words = 14.9 MB

__device__ inline unsigned short f2bf(float f) {
  unsigned u = __builtin_bit_cast(unsigned, f);
  u += 0x7FFF + ((u >> 16) & 1);          // RNE
  return (unsigned short)(u >> 16);
}
__device__ inline float bf2f(unsigned short u) {
  return __builtin_bit_cast(float, (unsigned)u << 16);
}

// ---------- fused init: zero gcur + W fp32->bf16 ----------
__global__ __launch_bounds__(256) void init_kernel(
    const float* __restrict__ W, unsigned int* __restrict__ wbf,
    int* __restrict__ gcur)
{
  int i = blockIdx.x * 256 + threadIdx.x;
  if (i < NIN * NHID / 2) {
    float2 w = reinterpret_cast<const float2*>(W)[i];
    wbf[i] = (unsigned)f2bf(w.x) | ((unsigned)f2bf(w.y) << 16);
  }
  if (i < NB) gcur[i] = 0;
}

// ---------- binA: coarse binning, LDS histogram, 1 reservation atomic/bucket
__global__ __launch_bounds__(256) void binA_kernel(
    const int* __restrict__ rows, const int* __restrict__ cols,
    const float* __restrict__ vals, int* __restrict__ gcur,
    int2* __restrict__ ecv2)
{
  __shared__ int hist[NB];
  __shared__ unsigned short slots[EB];
  int bid = blockIdx.x;
  int tid = (int)threadIdx.x;
  int e0 = bid * EB;

  for (int i = tid; i < NB; i += 256) hist[i] = 0;
  __syncthreads();
  #pragma unroll 4
  for (int k = 0; k < EB / 256; ++k) {
    int i = e0 + k * 256 + tid;
    if (i < NEDGES) {
      int r = rows[i];
      int s = atomicAdd(&hist[r >> 7], 1);
      slots[k * 256 + tid] = (unsigned short)s;
    }
  }
  __syncthreads();
  for (int i = tid; i < NB; i += 256) {
    int c = hist[i];
    hist[i] = c ? atomicAdd(&gcur[i], c) : 0;
  }
  __syncthreads();
  #pragma unroll 4
  for (int k = 0; k < EB / 256; ++k) {
    int i = e0 + k * 256 + tid;
    if (i < NEDGES) {
      int r = rows[i];
      int bkt = r >> 7;
      int sl = hist[bkt] + (int)slots[k * 256 + tid];
      if (sl < BCAP)
        ecv2[(long)bkt * BCAP + sl] =
            make_int2(cols[i] | ((r & 127) << 17), __float_as_int(vals[i]));
    }
  }
}

// ---------- MFMA GEMM: reg-staged LDS tile ----------------------------------
// 256 thr = 4 waves, 64 nodes/block. Stage: fp32 global (coalesced float4,
// load->cvt_pk->ds_write_b64 decoupled chain = deep MLP) into bf16 LDS tile
// [64][XSTR u32]. Then each wave MFMAs its 16 nodes from LDS (ds_read_b128,
// 16B-aligned rows, stride 268 -> <=2-way bank aliasing).
__global__ __launch_bounds__(256) void gemm_kernel(
    const float* __restrict__ x, const unsigned short* __restrict__ wbf,
    const float* __restrict__ b, unsigned short* __restrict__ h)
{
  __shared__ unsigned int xls[64 * XSTR];   // 68,608 B
  int blk = blockIdx.x;
  int tid = (int)threadIdx.x;

  // ---- stage 64 x 512 fp32 -> bf16 LDS (8192 float4, 32 per thread) ----
  #pragma unroll 8
  for (int c = 0; c < 32; ++c) {
    int idx = c * 256 + tid;        // float4 id, contiguous per iteration
    int lrow = idx >> 7;            // 128 float4 per row
    int k4 = idx & 127;
    long grow = (long)blk * 64 + lrow;
    if (grow >= NODES) grow = NODES - 1;    // dup-read, store guarded
    float4 v = *reinterpret_cast<const float4*>(x + grow * NIN + k4 * 4);
    unsigned lo, hi;
    asm("v_cvt_pk_bf16_f32 %0, %1, %2" : "=v"(lo) : "v"(v.x), "v"(v.y));
    asm("v_cvt_pk_bf16_f32 %0, %1, %2" : "=v"(hi) : "v"(v.z), "v"(v.w));
    *reinterpret_cast<uint2*>(&xls[lrow * XSTR + k4 * 2]) = make_uint2(lo, hi);
  }
  __syncthreads();

  // ---- compute: wave wv handles nodes blk*64 + wv*16 .. +15 ----
  int wv = tid >> 6;
  int lane = tid & 63;
  int r16 = lane & 15;                // A-row / D-col select
  int kg  = lane >> 4;                // k-group 0..3
  int lrow = wv * 16 + r16;
  const unsigned int* rowp = &xls[lrow * XSTR];
  const unsigned short* wp = wbf + (long)r16 * NIN + kg * 8;

  f32x4 acc[4] = {{0,0,0,0},{0,0,0,0},{0,0,0,0},{0,0,0,0}};

  #pragma unroll
  for (int m = 0; m < 16; ++m) {
    // bf16x8 fragment: floats m*32 + kg*8 .. +7  ->  u32 offset m*16 + kg*4
    uint4v ap = *reinterpret_cast<const uint4v*>(rowp + m * 16 + kg * 4);
    short8v af = __builtin_bit_cast(short8v, ap);
    #pragma unroll
    for (int ft = 0; ft < 4; ++ft) {
      short8v bfr = *reinterpret_cast<const short8v*>(
          wp + (long)ft * 16 * NIN + m * 32);
      acc[ft] = __builtin_amdgcn_mfma_f32_16x16x32_bf16(af, bfr, acc[ft], 0, 0, 0);
    }
  }

  // D: col(f) = lane&15, row(node-in-16) = kg*4 + reg
  int nbase = blk * 64 + wv * 16 + kg * 4;
  #pragma unroll
  for (int ft = 0; ft < 4; ++ft) {
    float bias = b[ft * 16 + r16];
    #pragma unroll
    for (int r = 0; r < 4; ++r) {
      int node = nbase + r;
      if (node < NODES)
        h[(long)node * NHID + ft * 16 + r16] = f2bf(acc[ft][r] + bias);
    }
  }
}

// ---------- sortb: counting-sort each bucket by row-local index -------------
__global__ __launch_bounds__(256) void sortb_kernel(
    const int* __restrict__ gcur, int2* __restrict__ ecv2,
    int2* __restrict__ rowmeta)
{
  __shared__ int2 ed[BCAP];               // 20.5 KB
  __shared__ unsigned short slots[BCAP];  // 5 KB
  __shared__ int hist[128], base[128], stmp[128];
  int bkt = blockIdx.x;
  int tid = (int)threadIdx.x;

  int n = gcur[bkt];
  if (n > BCAP) n = BCAP;
  int2* bptr = ecv2 + (long)bkt * BCAP;

  if (tid < 128) hist[tid] = 0;
  __syncthreads();

  for (int i = tid; i < n; i += 256) {
    int2 e = bptr[i];
    ed[i] = e;
    int rl = e.x >> 17;
    slots[i] = (unsigned short)atomicAdd(&hist[rl], 1);
  }
  __syncthreads();

  int v = (tid < 128) ? hist[tid] : 0;
  if (tid < 128) stmp[tid] = v;
  __syncthreads();
  for (int d = 1; d < 128; d <<= 1) {
    int t = (tid < 128 && tid >= d) ? stmp[tid - d] : 0;
    __syncthreads();
    if (tid < 128) stmp[tid] += t;
    __syncthreads();
  }
  if (tid < 128) base[tid] = stmp[tid] - v;
  __syncthreads();

  for (int i = tid; i < n; i += 256) {
    int2 e = ed[i];
    int rl = e.x >> 17;
    int pos = base[rl] + (int)slots[i];
    bptr[pos] = make_int2(e.x & 0x1FFFF, e.y);
  }

  if (tid < 128) {
    int row = bkt * 128 + tid;
    if (row < NODES)
      rowmeta[row] = make_int2(bkt * BCAP + base[tid], hist[tid]);
  }
}

// ---------- gather: wave per row, 8 edges in flight, +LeakyReLU -------------
__global__ __launch_bounds__(256) void gather_kernel(
    const int2* __restrict__ rowmeta, const int2* __restrict__ ecv2,
    const unsigned short* __restrict__ h, const float* __restrict__ alpha,
    float* __restrict__ out)
{
  int wid = (int)((blockIdx.x * 256 + threadIdx.x) >> 6);
  if (wid >= NODES) return;
  int lane = (int)(threadIdx.x & 63);
  int eg = lane >> 3;          // edge group 0..7
  int fo = lane & 7;           // feature octet 0..7
  int2 m = rowmeta[wid];
  int deg = m.y;
  const int2* base = ecv2 + m.x;
  float a = alpha[0];

  float acc[8] = {0.f, 0.f, 0.f, 0.f, 0.f, 0.f, 0.f, 0.f};
  int j = eg;
  int2 e = (j < deg) ? base[j] : make_int2(0, 0);
  while (j < deg) {
    int2 en = (j + 8 < deg) ? base[j + 8] : make_int2(0, 0);   // prefetch
    float v = __int_as_float(e.y);
    ushort8v hv = *reinterpret_cast<const ushort8v*>(&h[(long)e.x * NHID + fo * 8]);
    #pragma unroll
    for (int k = 0; k < 8; ++k)
      acc[k] = fmaf(v, bf2f(hv[k]), acc[k]);
    e = en;
    j += 8;
  }

  #pragma unroll
  for (int k = 0; k < 8; ++k) {
    acc[k] += __shfl_xor(acc[k], 8);
    acc[k] += __shfl_xor(acc[k], 16);
    acc[k] += __shfl_xor(acc[k], 32);
  }

  if (eg == 0) {
    float4 o0, o1;
    o0.x = acc[0] >= 0.f ? acc[0] : a * acc[0];
    o0.y = acc[1] >= 0.f ? acc[1] : a * acc[1];
    o0.z = acc[2] >= 0.f ? acc[2] : a * acc[2];
    o0.w = acc[3] >= 0.f ? acc[3] : a * acc[3];
    o1.x = acc[4] >= 0.f ? acc[4] : a * acc[4];
    o1.y = acc[5] >= 0.f ? acc[5] : a * acc[5];
    o1.z = acc[6] >= 0.f ? acc[6] : a * acc[6];
    o1.w = acc[7] >= 0.f ? acc[7] : a * acc[7];
    *reinterpret_cast<float4*>(&out[(long)wid * NHID + fo * 8]) = o0;
    *reinterpret_cast<float4*>(&out[(long)wid * NHID + fo * 8 + 4]) = o1;
  }
}

extern "C" void kernel_launch(void* const* d_in, const int* in_sizes, int n_in,
                              void* d_out, int out_size, void* d_ws, size_t ws_size,
                              hipStream_t stream) {
  const float* x     = (const float*)d_in[0];
  const int*   rows  = (const int*)d_in[1];
  const int*   cols  = (const int*)d_in[2];
  const float* vals  = (const float*)d_in[3];
  const float* W     = (const float*)d_in[4];
  const float* b     = (const float*)d_in[5];
  const float* alpha = (const float*)d_in[6];
  float* out = (float*)d_out;

  float* wsf = (float*)d_ws;
  unsigned short* h     = (unsigned short*)(wsf + H_OFF);
  unsigned int*   wbf   = (unsigned int*)(wsf + WBF_OFF);
  int*            gcur  = (int*)(wsf + GCUR_OFF);
  int2*           rmeta = (int2*)(wsf + RMETA_OFF);
  int2*           ecv2  = (int2*)(wsf + ECV2_OFF);

  init_kernel<<<64, 256, 0, stream>>>(W, wbf, gcur);
  binA_kernel<<<NBA, 256, 0, stream>>>(rows, cols, vals, gcur, ecv2);
  gemm_kernel<<<(NODES + 63) / 64, 256, 0, stream>>>(
      x, (const unsigned short*)wbf, b, h);
  sortb_kernel<<<NB, 256, 0, stream>>>(gcur, ecv2, rmeta);
  gather_kernel<<<NODES * 64 / 256, 256, 0, stream>>>(rmeta, ecv2, h, alpha, out);
}

// Round 16
// 99.820 us; speedup vs baseline: 1.0731x; 1.0731x over previous
//
#include <hip/hip_runtime.h>

#define NODES 50000
#define NEDGES 800000
#define NIN 512
#define NHID 64

#define NB 391        // coarse buckets: row >> 7, 128 rows each
#define BCAP 2560     // per-bucket edge capacity (mean 2046, +11 sigma)
#define EB 4096       // edges per binA block
#define NBA 196       // binA blocks: 196*4096 >= 800000

typedef __attribute__((ext_vector_type(8))) short short8v;           // 8 bf16
typedef __attribute__((ext_vector_type(8))) unsigned short ushort8v; // 8 bf16
typedef __attribute__((ext_vector_type(4))) float f32x4;
typedef __attribute__((ext_vector_type(4))) unsigned int uint4v;

// ws layout in 4-byte words
#define H_OFF    0          // 1,600,000 words: h bf16 (3.2M elems)
#define WBF_OFF  1600000    // 16,384 words: W bf16
#define GCUR_OFF 1616384    // 512 words: bucket cursors
#define RMETA_OFF 1616896   // 100,000 words: int2 {start, deg} per row
#define ECV2_OFF 1716896    // 2,001,920 words: NB x BCAP x int2
// end = 3,718,816 words = 14.9 MB

__device__ inline unsigned short f2bf(float f) {
  unsigned u = __builtin_bit_cast(unsigned, f);
  u += 0x7FFF + ((u >> 16) & 1);          // RNE
  return (unsigned short)(u >> 16);
}
__device__ inline float bf2f(unsigned short u) {
  return __builtin_bit_cast(float, (unsigned)u << 16);
}

// ---------- fused init: zero gcur + W fp32->bf16 ----------
__global__ __launch_bounds__(256) void init_kernel(
    const float* __restrict__ W, unsigned int* __restrict__ wbf,
    int* __restrict__ gcur)
{
  int i = blockIdx.x * 256 + threadIdx.x;
  if (i < NIN * NHID / 2) {
    float2 w = reinterpret_cast<const float2*>(W)[i];
    wbf[i] = (unsigned)f2bf(w.x) | ((unsigned)f2bf(w.y) << 16);
  }
  if (i < NB) gcur[i] = 0;
}

// ---------- binA: coarse binning, LDS histogram, 1 reservation atomic/bucket
__global__ __launch_bounds__(256) void binA_kernel(
    const int* __restrict__ rows, const int* __restrict__ cols,
    const float* __restrict__ vals, int* __restrict__ gcur,
    int2* __restrict__ ecv2)
{
  __shared__ int hist[NB];
  __shared__ unsigned short slots[EB];
  int bid = blockIdx.x;
  int tid = (int)threadIdx.x;
  int e0 = bid * EB;

  for (int i = tid; i < NB; i += 256) hist[i] = 0;
  __syncthreads();
  #pragma unroll 4
  for (int k = 0; k < EB / 256; ++k) {
    int i = e0 + k * 256 + tid;
    if (i < NEDGES) {
      int r = rows[i];
      int s = atomicAdd(&hist[r >> 7], 1);
      slots[k * 256 + tid] = (unsigned short)s;
    }
  }
  __syncthreads();
  for (int i = tid; i < NB; i += 256) {
    int c = hist[i];
    hist[i] = c ? atomicAdd(&gcur[i], c) : 0;
  }
  __syncthreads();
  #pragma unroll 4
  for (int k = 0; k < EB / 256; ++k) {
    int i = e0 + k * 256 + tid;
    if (i < NEDGES) {
      int r = rows[i];
      int bkt = r >> 7;
      int sl = hist[bkt] + (int)slots[k * 256 + tid];
      if (sl < BCAP)
        ecv2[(long)bkt * BCAP + sl] =
            make_int2(cols[i] | ((r & 127) << 17), __float_as_int(vals[i]));
    }
  }
}

// ---------- MFMA GEMM: 4-way K-split, 512 thr = 8 waves ---------------------
// 8 waves = 2 node-groups x 4 K-chunks (R15 bug: 256 thr is only 4 waves!).
// Wave (g,kc) MFMAs its 16 nodes over K [kc*128, kc*128+128) (8 x-loads).
// 1563 blocks x 8 = 12504 waves; 36.9KB LDS -> 4 blocks/CU = 32 waves/CU
// (HW cap) -> latency hidden by TLP. Partials summed via LDS.
__global__ __launch_bounds__(512) void gemm_kernel(
    const float* __restrict__ x, const unsigned short* __restrict__ wbf,
    const float* __restrict__ b, unsigned short* __restrict__ h)
{
  __shared__ float red[8][64][18];   // 36,864 B
  int blk = blockIdx.x;
  int tid = (int)threadIdx.x;
  int w = tid >> 6;                  // wave 0..7
  int lane = tid & 63;
  int g  = w & 1;                    // node group 0/1
  int kc = w >> 1;                   // K chunk 0..3
  int r16 = lane & 15;               // A-row / D-col select
  int kg  = lane >> 4;               // k-subgroup 0..3

  long row = (long)blk * 32 + g * 16 + r16;
  if (row >= NODES) row = NODES - 1;          // clamp loads; stores guarded
  const float* xp = x + row * NIN + kg * 8;
  const unsigned short* wp = wbf + (long)r16 * NIN + kg * 8;

  f32x4 acc[4] = {{0,0,0,0},{0,0,0,0},{0,0,0,0},{0,0,0,0}};

  #pragma unroll
  for (int m = 0; m < 4; ++m) {
    int M = kc * 4 + m;                       // global m-step 0..15
    float4 a0 = *reinterpret_cast<const float4*>(xp + M * 32);
    float4 a1 = *reinterpret_cast<const float4*>(xp + M * 32 + 4);
    unsigned q0, q1, q2, q3;   // v_cvt_pk_bf16_f32: lo=src0, hi=src1 (RNE)
    asm("v_cvt_pk_bf16_f32 %0, %1, %2" : "=v"(q0) : "v"(a0.x), "v"(a0.y));
    asm("v_cvt_pk_bf16_f32 %0, %1, %2" : "=v"(q1) : "v"(a0.z), "v"(a0.w));
    asm("v_cvt_pk_bf16_f32 %0, %1, %2" : "=v"(q2) : "v"(a1.x), "v"(a1.y));
    asm("v_cvt_pk_bf16_f32 %0, %1, %2" : "=v"(q3) : "v"(a1.z), "v"(a1.w));
    uint4v ap = {q0, q1, q2, q3};
    short8v af = __builtin_bit_cast(short8v, ap);
    #pragma unroll
    for (int ft = 0; ft < 4; ++ft) {
      short8v bfr = *reinterpret_cast<const short8v*>(
          wp + (long)ft * 16 * NIN + M * 32);
      acc[ft] = __builtin_amdgcn_mfma_f32_16x16x32_bf16(af, bfr, acc[ft], 0, 0, 0);
    }
  }

  // publish partials (float2 writes, 72B lane stride -> spread banks)
  #pragma unroll
  for (int ft = 0; ft < 4; ++ft) {
    *reinterpret_cast<float2*>(&red[w][lane][ft * 4]) =
        make_float2(acc[ft][0], acc[ft][1]);
    *reinterpret_cast<float2*>(&red[w][lane][ft * 4 + 2]) =
        make_float2(acc[ft][2], acc[ft][3]);
  }
  __syncthreads();

  // reduce 4 K-chunks + bias + store: 2048 outputs, 4 per thread
  #pragma unroll
  for (int j = 0; j < 4; ++j) {
    int o = tid * 4 + j;            // 0..2047
    int og  = o >> 10;              // node group
    int ol  = (o >> 4) & 63;        // source lane
    int idx = o & 15;               // ft*4 + r
    float s = red[0 * 2 + og][ol][idx] + red[1 * 2 + og][ol][idx]
            + red[2 * 2 + og][ol][idx] + red[3 * 2 + og][ol][idx];
    int ft = idx >> 2, r = idx & 3;
    int f = ft * 16 + (ol & 15);
    long node = (long)blk * 32 + og * 16 + (ol >> 4) * 4 + r;
    if (node < NODES)
      h[node * NHID + f] = f2bf(s + b[f]);
  }
}

// ---------- sortb: counting-sort each bucket by row-local index -------------
__global__ __launch_bounds__(256) void sortb_kernel(
    const int* __restrict__ gcur, int2* __restrict__ ecv2,
    int2* __restrict__ rowmeta)
{
  __shared__ int2 ed[BCAP];               // 20.5 KB
  __shared__ unsigned short slots[BCAP];  // 5 KB
  __shared__ int hist[128], base[128], stmp[128];
  int bkt = blockIdx.x;
  int tid = (int)threadIdx.x;

  int n = gcur[bkt];
  if (n > BCAP) n = BCAP;
  int2* bptr = ecv2 + (long)bkt * BCAP;

  if (tid < 128) hist[tid] = 0;
  __syncthreads();

  for (int i = tid; i < n; i += 256) {
    int2 e = bptr[i];
    ed[i] = e;
    int rl = e.x >> 17;
    slots[i] = (unsigned short)atomicAdd(&hist[rl], 1);
  }
  __syncthreads();

  int v = (tid < 128) ? hist[tid] : 0;
  if (tid < 128) stmp[tid] = v;
  __syncthreads();
  for (int d = 1; d < 128; d <<= 1) {
    int t = (tid < 128 && tid >= d) ? stmp[tid - d] : 0;
    __syncthreads();
    if (tid < 128) stmp[tid] += t;
    __syncthreads();
  }
  if (tid < 128) base[tid] = stmp[tid] - v;
  __syncthreads();

  for (int i = tid; i < n; i += 256) {
    int2 e = ed[i];
    int rl = e.x >> 17;
    int pos = base[rl] + (int)slots[i];
    bptr[pos] = make_int2(e.x & 0x1FFFF, e.y);
  }

  if (tid < 128) {
    int row = bkt * 128 + tid;
    if (row < NODES)
      rowmeta[row] = make_int2(bkt * BCAP + base[tid], hist[tid]);
  }
}

// ---------- gather: wave per row, 8 edges in flight, +LeakyReLU -------------
__global__ __launch_bounds__(256) void gather_kernel(
    const int2* __restrict__ rowmeta, const int2* __restrict__ ecv2,
    const unsigned short* __restrict__ h, const float* __restrict__ alpha,
    float* __restrict__ out)
{
  int wid = (int)((blockIdx.x * 256 + threadIdx.x) >> 6);
  if (wid >= NODES) return;
  int lane = (int)(threadIdx.x & 63);
  int eg = lane >> 3;          // edge group 0..7
  int fo = lane & 7;           // feature octet 0..7
  int2 m = rowmeta[wid];
  int deg = m.y;
  const int2* base = ecv2 + m.x;
  float a = alpha[0];

  float acc[8] = {0.f, 0.f, 0.f, 0.f, 0.f, 0.f, 0.f, 0.f};
  int j = eg;
  int2 e = (j < deg) ? base[j] : make_int2(0, 0);
  while (j < deg) {
    int2 en = (j + 8 < deg) ? base[j + 8] : make_int2(0, 0);   // prefetch
    float v = __int_as_float(e.y);
    ushort8v hv = *reinterpret_cast<const ushort8v*>(&h[(long)e.x * NHID + fo * 8]);
    #pragma unroll
    for (int k = 0; k < 8; ++k)
      acc[k] = fmaf(v, bf2f(hv[k]), acc[k]);
    e = en;
    j += 8;
  }

  #pragma unroll
  for (int k = 0; k < 8; ++k) {
    acc[k] += __shfl_xor(acc[k], 8);
    acc[k] += __shfl_xor(acc[k], 16);
    acc[k] += __shfl_xor(acc[k], 32);
  }

  if (eg == 0) {
    float4 o0, o1;
    o0.x = acc[0] >= 0.f ? acc[0] : a * acc[0];
    o0.y = acc[1] >= 0.f ? acc[1] : a * acc[1];
    o0.z = acc[2] >= 0.f ? acc[2] : a * acc[2];
    o0.w = acc[3] >= 0.f ? acc[3] : a * acc[3];
    o1.x = acc[4] >= 0.f ? acc[4] : a * acc[4];
    o1.y = acc[5] >= 0.f ? acc[5] : a * acc[5];
    o1.z = acc[6] >= 0.f ? acc[6] : a * acc[6];
    o1.w = acc[7] >= 0.f ? acc[7] : a * acc[7];
    *reinterpret_cast<float4*>(&out[(long)wid * NHID + fo * 8]) = o0;
    *reinterpret_cast<float4*>(&out[(long)wid * NHID + fo * 8 + 4]) = o1;
  }
}

extern "C" void kernel_launch(void* const* d_in, const int* in_sizes, int n_in,
                              void* d_out, int out_size, void* d_ws, size_t ws_size,
                              hipStream_t stream) {
  const float* x     = (const float*)d_in[0];
  const int*   rows  = (const int*)d_in[1];
  const int*   cols  = (const int*)d_in[2];
  const float* vals  = (const float*)d_in[3];
  const float* W     = (const float*)d_in[4];
  const float* b     = (const float*)d_in[5];
  const float* alpha = (const float*)d_in[6];
  float* out = (float*)d_out;

  float* wsf = (float*)d_ws;
  unsigned short* h     = (unsigned short*)(wsf + H_OFF);
  unsigned int*   wbf   = (unsigned int*)(wsf + WBF_OFF);
  int*            gcur  = (int*)(wsf + GCUR_OFF);
  int2*           rmeta = (int2*)(wsf + RMETA_OFF);
  int2*           ecv2  = (int2*)(wsf + ECV2_OFF);

  init_kernel<<<64, 256, 0, stream>>>(W, wbf, gcur);
  binA_kernel<<<NBA, 256, 0, stream>>>(rows, cols, vals, gcur, ecv2);
  gemm_kernel<<<(NODES + 31) / 32, 512, 0, stream>>>(
      x, (const unsigned short*)wbf, b, h);
  sortb_kernel<<<NB, 256, 0, stream>>>(gcur, ecv2, rmeta);
  gather_kernel<<<NODES * 64 / 256, 256, 0, stream>>>(rmeta, ecv2, h, alpha, out);
}